// Round 19
// baseline (132.725 us; speedup 1.0000x reference)
//
#include <hip/hip_runtime.h>

#define CC 32
#define DIM 24
#define SP (DIM*DIM*DIM)     // 13824
#define NPTS 27
#define M3 81
#define OUTC 64
#define BATCH 2
#define CN (CC*NPTS)         // 864 = K

#define VBB 12               // voxels per block, kernel B
#define NV (NPTS*VBB)        // 324 sample points per block
#define CPAD 896             // padded col row (XOR swizzle overflow space)
#define MP 84                // padded M for offset GEMM (81 -> 84)
#define XR 26                // x-halo row pitch, fully packed
#define HALOF (288*XR)       // 7488 floats of halo
#define CHUNKF 256           // chunk buffer stride in floats (252 used)

typedef __attribute__((ext_vector_type(8))) short short8;
typedef __attribute__((ext_vector_type(4))) float f32x4;

__device__ __forceinline__ unsigned short f2bf(float f) {
    unsigned u = __builtin_bit_cast(unsigned, f);
    return (unsigned short)((u + 0x7FFFu + ((u >> 16) & 1u)) >> 16);
}

// async global->LDS, 16B per lane, no destination VGPRs (un-defeatable
// prefetch: compiler has nothing to sink). Dest = lds base + lane*16.
__device__ __forceinline__ void gload16(const float* g, float* l) {
    __builtin_amdgcn_global_load_lds(
        (const __attribute__((address_space(1))) void*)g,
        (__attribute__((address_space(3))) void*)l, 16, 0, 0);
}

// ---------------- Kernel T1: weight prep ----------------
__global__ __launch_bounds__(256)
void prep_w_kernel(const float* __restrict__ p_w,
                   const float* __restrict__ conv_w,
                   float* __restrict__ p_wTP,
                   unsigned short* __restrict__ conv_wbf) {
    int id = blockIdx.x * 256 + threadIdx.x;
    if (id < CN * MP) {
        int k = id / MP, m = id % MP;
        p_wTP[id] = (m < M3) ? p_w[(size_t)m * CN + k] : 0.f;
    }
    if (id < CN * OUTC) {
        int o = id / CN, kp = id % CN;
        int n = kp >> 5, c = kp & 31;
        conv_wbf[id] = f2bf(conv_w[(size_t)o * CN + c * NPTS + n]);
    }
}

// ---------------- Kernel T2: x -> x_t[b][sp][c] (bf16, channel-minor) -------
__global__ __launch_bounds__(256)
void transpose_x_kernel(const float* __restrict__ x,
                        unsigned short* __restrict__ x_t) {
    __shared__ float tile[CC][65];
    int b = blockIdx.x / 216;
    int sp0 = (blockIdx.x % 216) * 64;
    const float* xb = x + (size_t)b * CC * SP;
    for (int it = threadIdx.x; it < CC * 64; it += 256) {
        int c = it >> 6, s = it & 63;
        tile[c][s] = xb[(size_t)c * SP + sp0 + s];
    }
    __syncthreads();
    unsigned short* xtb = x_t + (size_t)b * SP * CC;
    for (int it = threadIdx.x; it < CC * 64; it += 256) {
        int s = it >> 5, c = it & 31;
        xtb[(size_t)(sp0 + s) * CC + c] = f2bf(tile[c][s]);
    }
}

// ---------------- Kernel A: offset conv, LDS-streamed weights ---------------
// Block = (b,i,j) full k-row (24 voxels), grid 1152. 4-wave K-split; lane
// tile 4m x 8v. Weights stream via global_load_lds into per-wave
// double-buffered LDS chunks (3 rows = 1008 B): async DMA with NO dest
// VGPRs -> the prefetch cannot be sunk by the allocator (r8/r10/r15/r18:
// every register-level prefetch was silently defeated). Counted vmcnt(1)
// is safe: the K-loop contains no other VMEM (no spills at ~60 VGPR).
// LDS = halo 29952 + 4 waves x 2 x 1024 = 38144 B -> 4 blocks/CU.
__global__ __launch_bounds__(256, 4)
void offset_gemm_kernel(const float* __restrict__ x,
                        const float* __restrict__ p_wTP,
                        const float* __restrict__ p_b,
                        float* __restrict__ offset) {
    __shared__ __align__(16) float lds[HALOF + 4 * 2 * CHUNKF];  // 38144 B

    int bid = blockIdx.x;                    // 1152 = 2*24*24
    int j = bid % 24;
    int i = (bid / 24) % 24;
    int b = bid / 576;
    int sp0 = i * 576 + j * 24;
    int t = threadIdx.x;

    // --- x halo: lds[(c*9+dij)*26 + u] = x[b][c][i+di-1][j+dj-1][u-1] ---
    for (int it = t; it < 288 * 26; it += 256) {
        int row = it / 26, u = it % 26;
        int c = row / 9, dij = row % 9;
        int di = dij / 3, dj = dij % 3;
        int ii = i + di - 1, jj = j + dj - 1, kk = u - 1;
        bool v = ((unsigned)ii < (unsigned)DIM) && ((unsigned)jj < (unsigned)DIM) &&
                 ((unsigned)kk < (unsigned)DIM);
        lds[it] =
            v ? x[((size_t)(b * CC + c) * SP) + ii * 576 + jj * 24 + kk] : 0.f;
    }
    __syncthreads();                          // drains halo loads (vmcnt->0)

    // --- GEMM: wave w -> c in [8w,8w+8); lane mt(21) x vt(3); acc 4m x 8v ---
    int w = t >> 6, l = t & 63;
    int mt = l / 3, vt = l % 3;
    bool act = (l < 63);
    if (mt > 20) mt = 20;                    // lane 63: duplicate, store-guarded

    float acc[4][8];
    #pragma unroll
    for (int a = 0; a < 4; ++a)
        #pragma unroll
        for (int e = 0; e < 8; ++e) acc[a][e] = 0.f;

    const float* gw = p_wTP + (size_t)(w * 216) * MP;   // wave's weight slice
    const float* xbase = lds + (w * 72) * XR + vt * 8;
    float* cbase = lds + HALOF + w * 2 * CHUNKF;        // 2 chunk buffers

    // chunk = 3 weight rows = 252 floats, contiguous in p_wTP. 64 lanes x
    // 16 B: lane 63 over-stages 16 B of the NEXT chunk into the buffer's
    // 1008..1024 pad (never read); extreme tail source lands in the
    // adjacent conv_wbf ws region (valid memory, values unused).
    #define FMA_BODY(WB, CDIJ)                                              \
        do {                                                                \
            const float* xr = xbase + (CDIJ) * XR;                          \
            float2 x0 = *(const float2*)(xr);                               \
            float2 x1 = *(const float2*)(xr + 2);                           \
            float2 x2 = *(const float2*)(xr + 4);                           \
            float2 x3 = *(const float2*)(xr + 6);                           \
            float2 x4 = *(const float2*)(xr + 8);                           \
            float xv[10] = { x0.x, x0.y, x1.x, x1.y, x2.x, x2.y,            \
                             x3.x, x3.y, x4.x, x4.y };                      \
            _Pragma("unroll")                                               \
            for (int dk = 0; dk < 3; ++dk) {                                \
                float4 wv = *(const float4*)((WB) + dk * MP);               \
                _Pragma("unroll")                                           \
                for (int e = 0; e < 8; ++e) {                               \
                    float xvv = xv[dk + e];                                 \
                    acc[0][e] += wv.x * xvv;                                \
                    acc[1][e] += wv.y * xvv;                                \
                    acc[2][e] += wv.z * xvv;                                \
                    acc[3][e] += wv.w * xvv;                                \
                }                                                           \
            }                                                               \
        } while (0)

    gload16(gw + l * 4, cbase);              // chunk 0 -> buf 0 (1 in flight)

    int cur = 0;
    for (int cdij = 0; cdij < 72; ++cdij) {
        // issue chunk cdij+1 into the other buffer (2 in flight)
        gload16(gw + (size_t)(cdij + 1) * 252 + l * 4,
                cbase + (cur ^ 1) * CHUNKF);
        // wait until only the just-issued load remains -> chunk cdij landed
        asm volatile("s_waitcnt vmcnt(1)" ::: "memory");
        __builtin_amdgcn_sched_barrier(0);
        FMA_BODY(cbase + cur * CHUNKF + mt * 4, cdij);
        cur ^= 1;
    }
    #undef FMA_BODY
    // drain the dangling tail chunk before the LDS region is reused
    asm volatile("s_waitcnt vmcnt(0)" ::: "memory");
    __builtin_amdgcn_sched_barrier(0);
    __syncthreads();                          // x-halo reads done

    // --- partials, 2-round reduce in reused LDS: part[w2][m(84)][v(24)] ---
    float* part = lds;                        // 2*84*24*4 = 16128 B
    if (act && w < 2) {
        #pragma unroll
        for (int a = 0; a < 4; ++a) {
            #pragma unroll
            for (int e2 = 0; e2 < 2; ++e2) {
                float4 pv = make_float4(acc[a][e2 * 4], acc[a][e2 * 4 + 1],
                                        acc[a][e2 * 4 + 2], acc[a][e2 * 4 + 3]);
                *(float4*)&part[((w * MP) + mt * 4 + a) * 24 + vt * 8 + e2 * 4] = pv;
            }
        }
    }
    __syncthreads();
    if (act && w >= 2) {
        #pragma unroll
        for (int a = 0; a < 4; ++a) {
            #pragma unroll
            for (int e2 = 0; e2 < 2; ++e2) {
                float* dst = &part[(((w - 2) * MP) + mt * 4 + a) * 24 + vt * 8 + e2 * 4];
                float4 pv = *(const float4*)dst;
                pv.x += acc[a][e2 * 4];     pv.y += acc[a][e2 * 4 + 1];
                pv.z += acc[a][e2 * 4 + 2]; pv.w += acc[a][e2 * 4 + 3];
                *(float4*)dst = pv;
            }
        }
    }
    __syncthreads();

    // --- 2-way reduce + bias + store: 81 m x 6 float4-groups ---
    for (int it = t; it < M3 * 6; it += 256) {
        int m = it / 6, vq = it % 6;
        float4 p0 = *(const float4*)&part[(m) * 24 + vq * 4];
        float4 p1 = *(const float4*)&part[(MP + m) * 24 + vq * 4];
        float bias = p_b[m];
        float4 s = make_float4(p0.x + p1.x + bias, p0.y + p1.y + bias,
                               p0.z + p1.z + bias, p0.w + p1.w + bias);
        *(float4*)&offset[((size_t)(b * M3 + m)) * SP + sp0 + vq * 4] = s;
    }
}

// ------------- Kernel B: sample + project, 4-lane-per-point gather ----------
__global__ __launch_bounds__(256, 4)
void sample_gemm_kernel(const unsigned short* __restrict__ x_t,
                        const float* __restrict__ offset,
                        const unsigned short* __restrict__ conv_wbf,
                        float* __restrict__ out,     // [2, 64, SP]
                        float* __restrict__ p_out) { // [2, SP, 81]
    // region: col[12][896] bf16 (21504 B) then s_corner[8][324] u32 (10368 B)
    __shared__ __align__(16) unsigned char region[VBB * CPAD * 2 + 8 * NV * 4];
    unsigned short* col = (unsigned short*)region;
    unsigned* s_corner = (unsigned*)(region + VBB * CPAD * 2);

    int bid = blockIdx.x;                    // 2304 = 2*24*24*2
    int r = bid & 1;
    int j = (bid >> 1) % 24;
    int i = ((bid >> 1) / 24) % 24;
    int b = bid / 1152;
    int k0 = r * VBB;
    int sp0 = i * 576 + j * 24 + k0;
    int t = threadIdx.x;

    const unsigned short* xtb = x_t + (size_t)b * SP * CC;

    // --- phase 1: corners + p_out ---
    for (int it = t; it < NV; it += 256) {
        int v = it % VBB, n = it / VBB;
        int sp = sp0 + v;
        int k = k0 + v;

        int pnx = n / 9 - 1, pny = (n / 3) % 3 - 1, pnz = n % 3 - 1;
        float p0a[3] = { (float)(i + 1 + pnx),
                         (float)(j + 1 + pny),
                         (float)(k + 1 + pnz) };
        int ql[3], qh[3];
        float wl[3], wh[3];
        #pragma unroll
        for (int ax = 0; ax < 3; ++ax) {
            int m = ax * NPTS + n;
            float p = p0a[ax] + offset[((size_t)(b * M3 + m)) * SP + sp];
            float f = floorf(p);
            int qlo = (int)fminf(fmaxf(f,       0.f), 25.f);
            int qhi = (int)fminf(fmaxf(f + 1.f, 0.f), 25.f);
            bool oob = (p < 1.f) || (p > 24.f);
            float pa = oob ? f : p;
            float pm = fminf(fmaxf(pa, 0.f), 25.f);
            ql[ax] = qlo; qh[ax] = qhi;
            wl[ax] = 1.f + ((float)qlo - pm);
            wh[ax] = 1.f - ((float)qhi - pm);
            p_out[((size_t)(b * SP + sp)) * M3 + m] = pm;
        }

        #pragma unroll
        for (int cr = 0; cr < 8; ++cr) {
            int ii = ((cr & 4) ? qh[0] : ql[0]) - 1;
            int jj = ((cr & 2) ? qh[1] : ql[1]) - 1;
            int kk = ((cr & 1) ? qh[2] : ql[2]) - 1;
            bool valid = ((unsigned)ii < (unsigned)DIM) &&
                         ((unsigned)jj < (unsigned)DIM) &&
                         ((unsigned)kk < (unsigned)DIM);
            float cw = ((cr & 4) ? wh[0] : wl[0]) *
                       ((cr & 2) ? wh[1] : wl[1]) *
                       ((cr & 1) ? wh[2] : wl[2]);
            unsigned idx = (unsigned)(ii * 576 + jj * 24 + kk);
            s_corner[cr * NV + it] =
                valid ? ((idx << 16) | (unsigned)f2bf(cw)) : 0u;
        }
    }
    __syncthreads();

    // --- phase 2: gather; 4 lanes per item, lane owns 8-channel slice q ---
    for (int task = t; task < NV * 4; task += 256) {
        int item = task >> 2, q = task & 3;
        int v = item % VBB, n = item / VBB;

        const unsigned short* xq = xtb + q * 8;
        float acc[8];
        #pragma unroll
        for (int e = 0; e < 8; ++e) acc[e] = 0.f;

        #pragma unroll
        for (int cr = 0; cr < 8; ++cr) {
            unsigned u = s_corner[cr * NV + item];
            float wc = __builtin_bit_cast(float, u << 16);
            const unsigned* s = (const unsigned*)(xq + (size_t)(u >> 16) * CC);
            #pragma unroll
            for (int q2 = 0; q2 < 4; ++q2) {
                unsigned uu = s[q2];
                acc[2 * q2]     += wc * __builtin_bit_cast(float, uu << 16);
                acc[2 * q2 + 1] += wc * __builtin_bit_cast(float, uu & 0xFFFF0000u);
            }
        }

        short8 pk;
        #pragma unroll
        for (int e = 0; e < 8; ++e)
            pk[e] = (short)f2bf(acc[e]);
        int sv = (v & 7) << 3;
        *(short8*)&col[v * CPAD + ((n * 32 + q * 8) ^ sv)] = pk;
    }
    __syncthreads();

    // --- phase 3: MFMA GEMM 64 x 864 @ 864 x 12 ---
    {
        int mt = t >> 6;                      // wave -> M tile (16 rows)
        int l = t & 63;
        int lr = l & 15;                      // A row / B col (voxel)
        int g = l >> 4;
        int sv = (lr & 7) << 3;

        const short8* ap =
            (const short8*)(conv_wbf + ((size_t)(mt * 16 + lr)) * CN + g * 8);
        const unsigned short* bp = col + lr * CPAD;

        f32x4 acc = {0.f, 0.f, 0.f, 0.f};
        #pragma unroll 3
        for (int kb = 0; kb < CN / 32; ++kb) {
            short8 a = ap[kb * 4];
            short8 bb = *(const short8*)&bp[(kb * 32 + g * 8) ^ sv];
            acc = __builtin_amdgcn_mfma_f32_16x16x32_bf16(a, bb, acc, 0, 0, 0);
        }
        if (lr < VBB) {
            float* op = out + ((size_t)(b * OUTC + mt * 16 + g * 4)) * SP + sp0 + lr;
            #pragma unroll
            for (int rr = 0; rr < 4; ++rr)
                op[(size_t)rr * SP] = acc[rr];
        }
    }
}

extern "C" void kernel_launch(void* const* d_in, const int* in_sizes, int n_in,
                              void* d_out, int out_size, void* d_ws, size_t ws_size,
                              hipStream_t stream) {
    const float* x      = (const float*)d_in[0];
    const float* p_w    = (const float*)d_in[1];
    const float* p_b    = (const float*)d_in[2];
    const float* conv_w = (const float*)d_in[3];

    float* out_all = (float*)d_out;
    float* out_main = out_all;                               // [2,64,13824]
    float* p_out    = out_all + (size_t)BATCH * OUTC * SP;   // [2,13824,81]

    float* offset          = (float*)d_ws;                   // [2,81,13824]
    float* p_wTP           = offset + (size_t)BATCH * M3 * SP;
    unsigned short* conv_wbf = (unsigned short*)(p_wTP + (size_t)CN * MP);
    unsigned short* x_t    = conv_wbf + (size_t)CN * OUTC;   // [2,13824,32] bf16

    {
        int total = CN * MP;                                 // 72576 covers both
        prep_w_kernel<<<(total + 255) / 256, 256, 0, stream>>>(p_w, conv_w,
                                                               p_wTP, conv_wbf);
    }
    {
        int blocks = BATCH * (SP / 64);                      // 432
        transpose_x_kernel<<<blocks, 256, 0, stream>>>(x, x_t);
    }
    {
        int blocks = BATCH * 24 * 24;                        // 1152
        offset_gemm_kernel<<<blocks, 256, 0, stream>>>(x, p_wTP, p_b, offset);
    }
    {
        int blocks = BATCH * 24 * 24 * 2;                    // 2304
        sample_gemm_kernel<<<blocks, 256, 0, stream>>>(x_t, offset, conv_wbf,
                                                       out_main, p_out);
    }
}

// Round 20
// 123.475 us; speedup vs baseline: 1.0749x; 1.0749x over previous
//
#include <hip/hip_runtime.h>

#define CC 32
#define DIM 24
#define SP (DIM*DIM*DIM)     // 13824
#define NPTS 27
#define M3 81
#define OUTC 64
#define BATCH 2
#define CN (CC*NPTS)         // 864 = K

#define VBB 12               // voxels per block, kernel B
#define NV (NPTS*VBB)        // 324 sample points per block
#define CPAD 896             // padded col row (XOR swizzle overflow space)
#define MP 84                // padded M for offset GEMM (81 -> 84)
#define HROW 26              // halo k-pitch (fully packed, float2-aligned)
#define HALOF (32*3*4*HROW)  // 9984 floats = 39936 B

typedef __attribute__((ext_vector_type(8))) short short8;
typedef __attribute__((ext_vector_type(4))) float f32x4;

__device__ __forceinline__ unsigned short f2bf(float f) {
    unsigned u = __builtin_bit_cast(unsigned, f);
    return (unsigned short)((u + 0x7FFFu + ((u >> 16) & 1u)) >> 16);
}

// ---------------- Kernel T1: weight prep ----------------
__global__ __launch_bounds__(256)
void prep_w_kernel(const float* __restrict__ p_w,
                   const float* __restrict__ conv_w,
                   float* __restrict__ p_wTP,
                   unsigned short* __restrict__ conv_wbf) {
    int id = blockIdx.x * 256 + threadIdx.x;
    if (id < CN * MP) {
        int k = id / MP, m = id % MP;
        p_wTP[id] = (m < M3) ? p_w[(size_t)m * CN + k] : 0.f;
    }
    if (id < CN * OUTC) {
        int o = id / CN, kp = id % CN;
        int n = kp >> 5, c = kp & 31;
        conv_wbf[id] = f2bf(conv_w[(size_t)o * CN + c * NPTS + n]);
    }
}

// ---------------- Kernel T2: x -> x_t[b][sp][c] (bf16, channel-minor) -------
__global__ __launch_bounds__(256)
void transpose_x_kernel(const float* __restrict__ x,
                        unsigned short* __restrict__ x_t) {
    __shared__ float tile[CC][65];
    int b = blockIdx.x / 216;
    int sp0 = (blockIdx.x % 216) * 64;
    const float* xb = x + (size_t)b * CC * SP;
    for (int it = threadIdx.x; it < CC * 64; it += 256) {
        int c = it >> 6, s = it & 63;
        tile[c][s] = xb[(size_t)c * SP + sp0 + s];
    }
    __syncthreads();
    unsigned short* xtb = x_t + (size_t)b * SP * CC;
    for (int it = threadIdx.x; it < CC * 64; it += 256) {
        int s = it >> 5, c = it & 31;
        xtb[(size_t)(sp0 + s) * CC + c] = f2bf(tile[c][s]);
    }
}

// ---------------- Kernel A: offset conv, 48-voxel / 8-wave form -------------
// Block = (b, i, j-pair): 2 adjacent j-rows = 48 voxels, grid 576, 512 thr.
// Shared halo [32c][3di][4jq][26] (j-halos overlap) = 39936 B.
// 8-wave c-split (4 ch/wave, 36 iters); lane tile 4m x 8v x 2 j-rows ->
// 64 FMA per weight float4 (2x r13's intensity; weight L2 traffic halved)
// and ~4 waves/SIMD steady-state TLP (2x r13's measured 2.4).
// Partials reduce in 4 LDS rounds ([2][84][48] = 32256 B, reuses halo).
__global__ __launch_bounds__(512, 4)
void offset_gemm_kernel(const float* __restrict__ x,
                        const float* __restrict__ p_wTP,
                        const float* __restrict__ p_b,
                        float* __restrict__ offset) {
    __shared__ float lds[HALOF];             // 39936 B

    int bid = blockIdx.x;                    // 576 = 2*24*12
    int jp = bid % 12;
    int i  = (bid / 12) % 24;
    int b  = bid / 288;
    int j0 = jp * 2;
    int sp0 = i * 576 + j0 * 24;             // 48 contiguous voxels
    int t = threadIdx.x;

    // --- halo: lds[((c*3+di)*4+jq)*26 + u] = x[b][c][i+di-1][j0-1+jq][u-1]
    for (int it = t; it < HALOF; it += 512) {
        int rh = it / HROW, u = it - rh * HROW;
        int c = rh / 12, r2 = rh - c * 12;
        int di = r2 >> 2, jq = r2 & 3;
        int ii = i + di - 1, jj = j0 - 1 + jq, kk = u - 1;
        bool v = ((unsigned)ii < (unsigned)DIM) && ((unsigned)jj < (unsigned)DIM) &&
                 ((unsigned)kk < (unsigned)DIM);
        lds[it] =
            v ? x[((size_t)(b * CC + c) * SP) + ii * 576 + jj * 24 + kk] : 0.f;
    }
    __syncthreads();

    // --- GEMM: wave w -> c in [4w,4w+4); lane mt(21) x vt(3); 2 j-rows ---
    int w = t >> 6, l = t & 63;
    int mt = l / 3, vt = l % 3;
    bool act = (l < 63);
    if (mt > 20) mt = 20;                    // lane 63: duplicate, store-guarded

    float acc[4][8], ac2[4][8];
    #pragma unroll
    for (int a = 0; a < 4; ++a)
        #pragma unroll
        for (int e = 0; e < 8; ++e) { acc[a][e] = 0.f; ac2[a][e] = 0.f; }

    const float* gw = p_wTP + (size_t)(w * 108) * MP + mt * 4;  // wave's rows

    for (int cdij = 0; cdij < 36; ++cdij) {
        int c = 4 * w + cdij / 9;
        int dij = cdij % 9;
        int di = dij / 3, dj = dij % 3;
        const float* xrA = lds + ((c * 3 + di) * 4 + dj) * HROW + vt * 8;
        const float* xrB = xrA + HROW;       // jq = dj+1 row

        float2 a0 = *(const float2*)(xrA);
        float2 a1 = *(const float2*)(xrA + 2);
        float2 a2 = *(const float2*)(xrA + 4);
        float2 a3 = *(const float2*)(xrA + 6);
        float2 a4 = *(const float2*)(xrA + 8);
        float xvA[10] = { a0.x, a0.y, a1.x, a1.y, a2.x, a2.y,
                          a3.x, a3.y, a4.x, a4.y };
        float2 b0 = *(const float2*)(xrB);
        float2 b1 = *(const float2*)(xrB + 2);
        float2 b2 = *(const float2*)(xrB + 4);
        float2 b3 = *(const float2*)(xrB + 6);
        float2 b4 = *(const float2*)(xrB + 8);
        float xvB[10] = { b0.x, b0.y, b1.x, b1.y, b2.x, b2.y,
                          b3.x, b3.y, b4.x, b4.y };

        const float* wr = gw + (size_t)(cdij * 3) * MP;
        #pragma unroll
        for (int dk = 0; dk < 3; ++dk) {
            float4 wv = *(const float4*)(wr + (size_t)dk * MP);
            #pragma unroll
            for (int e = 0; e < 8; ++e) {
                float xa = xvA[dk + e];
                float xb = xvB[dk + e];
                acc[0][e] += wv.x * xa;  ac2[0][e] += wv.x * xb;
                acc[1][e] += wv.y * xa;  ac2[1][e] += wv.y * xb;
                acc[2][e] += wv.z * xa;  ac2[2][e] += wv.z * xb;
                acc[3][e] += wv.w * xa;  ac2[3][e] += wv.w * xb;
            }
        }
    }
    __syncthreads();                          // halo reads done

    // --- partials: part[w2][m(84)][v(48)] = 32256 B (reuse lds) ---
    // v = jrow*24 + vt*8 + e
    float* part = lds;
    #define STORE_P(W)                                                      \
        do {                                                                \
            float* dst = &part[((W) * MP + mt * 4) * 48 + vt * 8];          \
            _Pragma("unroll")                                               \
            for (int a = 0; a < 4; ++a) {                                   \
                _Pragma("unroll")                                           \
                for (int e2 = 0; e2 < 2; ++e2) {                            \
                    *(float4*)&dst[a * 48 + e2 * 4] =                       \
                        make_float4(acc[a][e2*4], acc[a][e2*4+1],           \
                                    acc[a][e2*4+2], acc[a][e2*4+3]);        \
                    *(float4*)&dst[a * 48 + 24 + e2 * 4] =                  \
                        make_float4(ac2[a][e2*4], ac2[a][e2*4+1],           \
                                    ac2[a][e2*4+2], ac2[a][e2*4+3]);        \
                }                                                           \
            }                                                               \
        } while (0)
    #define ADD_P(W)                                                       \
        do {                                                                \
            float* dst = &part[((W) * MP + mt * 4) * 48 + vt * 8];          \
            _Pragma("unroll")                                               \
            for (int a = 0; a < 4; ++a) {                                   \
                _Pragma("unroll")                                           \
                for (int e2 = 0; e2 < 2; ++e2) {                            \
                    float4 p = *(const float4*)&dst[a * 48 + e2 * 4];       \
                    p.x += acc[a][e2*4];   p.y += acc[a][e2*4+1];           \
                    p.z += acc[a][e2*4+2]; p.w += acc[a][e2*4+3];           \
                    *(float4*)&dst[a * 48 + e2 * 4] = p;                    \
                    float4 q = *(const float4*)&dst[a * 48 + 24 + e2 * 4];  \
                    q.x += ac2[a][e2*4];   q.y += ac2[a][e2*4+1];           \
                    q.z += ac2[a][e2*4+2]; q.w += ac2[a][e2*4+3];           \
                    *(float4*)&dst[a * 48 + 24 + e2 * 4] = q;               \
                }                                                           \
            }                                                               \
        } while (0)

    if (act && w < 2) STORE_P(w);
    __syncthreads();
    if (act && (w == 2 || w == 3)) ADD_P(w - 2);
    __syncthreads();
    if (act && (w == 4 || w == 5)) ADD_P(w - 4);
    __syncthreads();
    if (act && (w == 6 || w == 7)) ADD_P(w - 6);
    __syncthreads();
    #undef STORE_P
    #undef ADD_P

    // --- 2-way reduce + bias + store: 81 m x 12 float4-groups (48 vox) ---
    for (int it = t; it < M3 * 12; it += 512) {
        int m = it / 12, vq = it % 12;
        float4 p0 = *(const float4*)&part[(m) * 48 + vq * 4];
        float4 p1 = *(const float4*)&part[(MP + m) * 48 + vq * 4];
        float bias = p_b[m];
        float4 s = make_float4(p0.x + p1.x + bias, p0.y + p1.y + bias,
                               p0.z + p1.z + bias, p0.w + p1.w + bias);
        *(float4*)&offset[((size_t)(b * M3 + m)) * SP + sp0 + vq * 4] = s;
    }
}

// ------------- Kernel B: sample + project, 4-lane-per-point gather ----------
__global__ __launch_bounds__(256, 4)
void sample_gemm_kernel(const unsigned short* __restrict__ x_t,
                        const float* __restrict__ offset,
                        const unsigned short* __restrict__ conv_wbf,
                        float* __restrict__ out,     // [2, 64, SP]
                        float* __restrict__ p_out) { // [2, SP, 81]
    // region: col[12][896] bf16 (21504 B) then s_corner[8][324] u32 (10368 B)
    __shared__ __align__(16) unsigned char region[VBB * CPAD * 2 + 8 * NV * 4];
    unsigned short* col = (unsigned short*)region;
    unsigned* s_corner = (unsigned*)(region + VBB * CPAD * 2);

    int bid = blockIdx.x;                    // 2304 = 2*24*24*2
    int r = bid & 1;
    int j = (bid >> 1) % 24;
    int i = ((bid >> 1) / 24) % 24;
    int b = bid / 1152;
    int k0 = r * VBB;
    int sp0 = i * 576 + j * 24 + k0;
    int t = threadIdx.x;

    const unsigned short* xtb = x_t + (size_t)b * SP * CC;

    // --- phase 1: corners + p_out ---
    for (int it = t; it < NV; it += 256) {
        int v = it % VBB, n = it / VBB;
        int sp = sp0 + v;
        int k = k0 + v;

        int pnx = n / 9 - 1, pny = (n / 3) % 3 - 1, pnz = n % 3 - 1;
        float p0a[3] = { (float)(i + 1 + pnx),
                         (float)(j + 1 + pny),
                         (float)(k + 1 + pnz) };
        int ql[3], qh[3];
        float wl[3], wh[3];
        #pragma unroll
        for (int ax = 0; ax < 3; ++ax) {
            int m = ax * NPTS + n;
            float p = p0a[ax] + offset[((size_t)(b * M3 + m)) * SP + sp];
            float f = floorf(p);
            int qlo = (int)fminf(fmaxf(f,       0.f), 25.f);
            int qhi = (int)fminf(fmaxf(f + 1.f, 0.f), 25.f);
            bool oob = (p < 1.f) || (p > 24.f);
            float pa = oob ? f : p;
            float pm = fminf(fmaxf(pa, 0.f), 25.f);
            ql[ax] = qlo; qh[ax] = qhi;
            wl[ax] = 1.f + ((float)qlo - pm);
            wh[ax] = 1.f - ((float)qhi - pm);
            p_out[((size_t)(b * SP + sp)) * M3 + m] = pm;
        }

        #pragma unroll
        for (int cr = 0; cr < 8; ++cr) {
            int ii = ((cr & 4) ? qh[0] : ql[0]) - 1;
            int jj = ((cr & 2) ? qh[1] : ql[1]) - 1;
            int kk = ((cr & 1) ? qh[2] : ql[2]) - 1;
            bool valid = ((unsigned)ii < (unsigned)DIM) &&
                         ((unsigned)jj < (unsigned)DIM) &&
                         ((unsigned)kk < (unsigned)DIM);
            float cw = ((cr & 4) ? wh[0] : wl[0]) *
                       ((cr & 2) ? wh[1] : wl[1]) *
                       ((cr & 1) ? wh[2] : wl[2]);
            unsigned idx = (unsigned)(ii * 576 + jj * 24 + kk);
            s_corner[cr * NV + it] =
                valid ? ((idx << 16) | (unsigned)f2bf(cw)) : 0u;
        }
    }
    __syncthreads();

    // --- phase 2: gather; 4 lanes per item, lane owns 8-channel slice q ---
    for (int task = t; task < NV * 4; task += 256) {
        int item = task >> 2, q = task & 3;
        int v = item % VBB, n = item / VBB;

        const unsigned short* xq = xtb + q * 8;
        float acc[8];
        #pragma unroll
        for (int e = 0; e < 8; ++e) acc[e] = 0.f;

        #pragma unroll
        for (int cr = 0; cr < 8; ++cr) {
            unsigned u = s_corner[cr * NV + item];
            float wc = __builtin_bit_cast(float, u << 16);
            const unsigned* s = (const unsigned*)(xq + (size_t)(u >> 16) * CC);
            #pragma unroll
            for (int q2 = 0; q2 < 4; ++q2) {
                unsigned uu = s[q2];
                acc[2 * q2]     += wc * __builtin_bit_cast(float, uu << 16);
                acc[2 * q2 + 1] += wc * __builtin_bit_cast(float, uu & 0xFFFF0000u);
            }
        }

        short8 pk;
        #pragma unroll
        for (int e = 0; e < 8; ++e)
            pk[e] = (short)f2bf(acc[e]);
        int sv = (v & 7) << 3;
        *(short8*)&col[v * CPAD + ((n * 32 + q * 8) ^ sv)] = pk;
    }
    __syncthreads();

    // --- phase 3: MFMA GEMM 64 x 864 @ 864 x 12 ---
    {
        int mt = t >> 6;                      // wave -> M tile (16 rows)
        int l = t & 63;
        int lr = l & 15;                      // A row / B col (voxel)
        int g = l >> 4;
        int sv = (lr & 7) << 3;

        const short8* ap =
            (const short8*)(conv_wbf + ((size_t)(mt * 16 + lr)) * CN + g * 8);
        const unsigned short* bp = col + lr * CPAD;

        f32x4 acc = {0.f, 0.f, 0.f, 0.f};
        #pragma unroll 3
        for (int kb = 0; kb < CN / 32; ++kb) {
            short8 a = ap[kb * 4];
            short8 bb = *(const short8*)&bp[(kb * 32 + g * 8) ^ sv];
            acc = __builtin_amdgcn_mfma_f32_16x16x32_bf16(a, bb, acc, 0, 0, 0);
        }
        if (lr < VBB) {
            float* op = out + ((size_t)(b * OUTC + mt * 16 + g * 4)) * SP + sp0 + lr;
            #pragma unroll
            for (int rr = 0; rr < 4; ++rr)
                op[(size_t)rr * SP] = acc[rr];
        }
    }
}

extern "C" void kernel_launch(void* const* d_in, const int* in_sizes, int n_in,
                              void* d_out, int out_size, void* d_ws, size_t ws_size,
                              hipStream_t stream) {
    const float* x      = (const float*)d_in[0];
    const float* p_w    = (const float*)d_in[1];
    const float* p_b    = (const float*)d_in[2];
    const float* conv_w = (const float*)d_in[3];

    float* out_all = (float*)d_out;
    float* out_main = out_all;                               // [2,64,13824]
    float* p_out    = out_all + (size_t)BATCH * OUTC * SP;   // [2,13824,81]

    float* offset          = (float*)d_ws;                   // [2,81,13824]
    float* p_wTP           = offset + (size_t)BATCH * M3 * SP;
    unsigned short* conv_wbf = (unsigned short*)(p_wTP + (size_t)CN * MP);
    unsigned short* x_t    = conv_wbf + (size_t)CN * OUTC;   // [2,13824,32] bf16

    {
        int total = CN * MP;                                 // 72576 covers both
        prep_w_kernel<<<(total + 255) / 256, 256, 0, stream>>>(p_w, conv_w,
                                                               p_wTP, conv_wbf);
    }
    {
        int blocks = BATCH * (SP / 64);                      // 432
        transpose_x_kernel<<<blocks, 256, 0, stream>>>(x, x_t);
    }
    {
        int blocks = BATCH * 24 * 12;                        // 576
        offset_gemm_kernel<<<blocks, 512, 0, stream>>>(x, p_wTP, p_b, offset);
    }
    {
        int blocks = BATCH * 24 * 24 * 2;                    // 2304
        sample_gemm_kernel<<<blocks, 256, 0, stream>>>(x_t, offset, conv_wbf,
                                                       out_main, p_out);
    }
}

// Round 21
// 116.447 us; speedup vs baseline: 1.1398x; 1.0604x over previous
//
#include <hip/hip_runtime.h>

#define CC 32
#define DIM 24
#define SP (DIM*DIM*DIM)     // 13824
#define NPTS 27
#define M3 81
#define OUTC 64
#define BATCH 2
#define CN (CC*NPTS)         // 864 = K

#define VBB 12               // voxels per block, kernel B
#define NV (NPTS*VBB)        // 324 sample points per block
#define CPAD 896             // padded col row (XOR swizzle overflow space)
#define MP 84                // padded M for offset GEMM (81 -> 84)
#define XR 26                // x-halo row pitch, fully packed

typedef __attribute__((ext_vector_type(8))) short short8;
typedef __attribute__((ext_vector_type(4))) float f32x4;

__device__ __forceinline__ unsigned short f2bf(float f) {
    unsigned u = __builtin_bit_cast(unsigned, f);
    return (unsigned short)((u + 0x7FFFu + ((u >> 16) & 1u)) >> 16);
}

// ---------------- Kernel T1: weight prep ----------------
__global__ __launch_bounds__(256)
void prep_w_kernel(const float* __restrict__ p_w,
                   const float* __restrict__ conv_w,
                   float* __restrict__ p_wTP,
                   unsigned short* __restrict__ conv_wbf) {
    int id = blockIdx.x * 256 + threadIdx.x;
    if (id < CN * MP) {
        int k = id / MP, m = id % MP;
        p_wTP[id] = (m < M3) ? p_w[(size_t)m * CN + k] : 0.f;
    }
    if (id < CN * OUTC) {
        int o = id / CN, kp = id % CN;
        int n = kp >> 5, c = kp & 31;
        conv_wbf[id] = f2bf(conv_w[(size_t)o * CN + c * NPTS + n]);
    }
}

// ---------------- Kernel T2: x -> x_t[b][sp][c] (bf16, channel-minor) -------
__global__ __launch_bounds__(256)
void transpose_x_kernel(const float* __restrict__ x,
                        unsigned short* __restrict__ x_t) {
    __shared__ float tile[CC][65];
    int b = blockIdx.x / 216;
    int sp0 = (blockIdx.x % 216) * 64;
    const float* xb = x + (size_t)b * CC * SP;
    for (int it = threadIdx.x; it < CC * 64; it += 256) {
        int c = it >> 6, s = it & 63;
        tile[c][s] = xb[(size_t)c * SP + sp0 + s];
    }
    __syncthreads();
    unsigned short* xtb = x_t + (size_t)b * SP * CC;
    for (int it = threadIdx.x; it < CC * 64; it += 256) {
        int s = it >> 5, c = it & 31;
        xtb[(size_t)(sp0 + s) * CC + c] = f2bf(tile[c][s]);
    }
}

// ---------------- Kernel A: offset conv (r13/r15 structure, best: 72us) -----
// Block = (b,i,j) full k-row (24 voxels), grid 1152. LDS = packed x halo
// [288][26] fp32 = 29952 B -> 5 blocks/CU. 4-wave K-split (8 ch/wave);
// lane tile 4m x 8v (32 FMA per weight float4). Converged minimum of 9
// structural variants (r5-r20); remaining gap to the 26us FMA floor is
// the compiler's sink-at-use weight stream (unfixable at source level:
// C-prefetch defeated x4, asm racy x2, global_load_lds slower x1).
__global__ __launch_bounds__(256, 5)
void offset_gemm_kernel(const float* __restrict__ x,
                        const float* __restrict__ p_wTP,
                        const float* __restrict__ p_b,
                        float* __restrict__ offset) {
    __shared__ float lds[288 * XR];          // 29952 B

    int bid = blockIdx.x;                    // 1152 = 2*24*24
    int j = bid % 24;
    int i = (bid / 24) % 24;
    int b = bid / 576;
    int sp0 = i * 576 + j * 24;
    int t = threadIdx.x;

    for (int it = t; it < 288 * 26; it += 256) {
        int row = it / 26, u = it % 26;
        int c = row / 9, dij = row % 9;
        int di = dij / 3, dj = dij % 3;
        int ii = i + di - 1, jj = j + dj - 1, kk = u - 1;
        bool v = ((unsigned)ii < (unsigned)DIM) && ((unsigned)jj < (unsigned)DIM) &&
                 ((unsigned)kk < (unsigned)DIM);
        lds[it] =
            v ? x[((size_t)(b * CC + c) * SP) + ii * 576 + jj * 24 + kk] : 0.f;
    }
    __syncthreads();

    int w = t >> 6, l = t & 63;
    int mt = l / 3, vt = l % 3;
    bool act = (l < 63);
    if (mt > 20) mt = 20;                    // lane 63: duplicate, store-guarded

    float acc[4][8];
    #pragma unroll
    for (int a = 0; a < 4; ++a)
        #pragma unroll
        for (int e = 0; e < 8; ++e) acc[a][e] = 0.f;

    const float* wbase = p_wTP + (size_t)(w * 216) * MP + mt * 4;
    const float* xbase = lds + (w * 72) * XR + vt * 8;

    float4 pwA[3], pwB[3];
    #pragma unroll
    for (int dk = 0; dk < 3; ++dk)
        pwA[dk] = *(const float4*)(wbase + (size_t)dk * MP);

    #define FMA_BODY(PW, CDIJ)                                              \
        do {                                                                \
            const float* xr = xbase + (CDIJ) * XR;                          \
            float2 x0 = *(const float2*)(xr);                               \
            float2 x1 = *(const float2*)(xr + 2);                           \
            float2 x2 = *(const float2*)(xr + 4);                           \
            float2 x3 = *(const float2*)(xr + 6);                           \
            float2 x4 = *(const float2*)(xr + 8);                           \
            float xv[10] = { x0.x, x0.y, x1.x, x1.y, x2.x, x2.y,            \
                             x3.x, x3.y, x4.x, x4.y };                      \
            _Pragma("unroll")                                               \
            for (int dk = 0; dk < 3; ++dk) {                                \
                float4 wv = PW[dk];                                         \
                _Pragma("unroll")                                           \
                for (int e = 0; e < 8; ++e) {                               \
                    float xvv = xv[dk + e];                                 \
                    acc[0][e] += wv.x * xvv;                                \
                    acc[1][e] += wv.y * xvv;                                \
                    acc[2][e] += wv.z * xvv;                                \
                    acc[3][e] += wv.w * xvv;                                \
                }                                                           \
            }                                                               \
        } while (0)

    for (int cdij = 0; cdij < 72; cdij += 2) {
        {   // even: issue prefetch of cdij+1 into pwB, pin, compute cdij
            const float* wn = wbase + (size_t)((cdij + 1) * 3) * MP;
            #pragma unroll
            for (int dk = 0; dk < 3; ++dk)
                pwB[dk] = *(const float4*)(wn + (size_t)dk * MP);
            __builtin_amdgcn_sched_barrier(0);
            FMA_BODY(pwA, cdij);
        }
        {   // odd: prefetch cdij+2 into pwA; tail overreads land in the
            // adjacent conv_wbf ws region (valid memory, values unused).
            const float* wn = wbase + (size_t)((cdij + 2) * 3) * MP;
            #pragma unroll
            for (int dk = 0; dk < 3; ++dk)
                pwA[dk] = *(const float4*)(wn + (size_t)dk * MP);
            __builtin_amdgcn_sched_barrier(0);
            FMA_BODY(pwB, cdij + 1);
        }
    }
    #undef FMA_BODY
    __syncthreads();

    float* part = lds;                        // 2*84*24*4 = 16128 B
    if (act && w < 2) {
        #pragma unroll
        for (int a = 0; a < 4; ++a) {
            #pragma unroll
            for (int e2 = 0; e2 < 2; ++e2) {
                float4 pv = make_float4(acc[a][e2 * 4], acc[a][e2 * 4 + 1],
                                        acc[a][e2 * 4 + 2], acc[a][e2 * 4 + 3]);
                *(float4*)&part[((w * MP) + mt * 4 + a) * 24 + vt * 8 + e2 * 4] = pv;
            }
        }
    }
    __syncthreads();
    if (act && w >= 2) {
        #pragma unroll
        for (int a = 0; a < 4; ++a) {
            #pragma unroll
            for (int e2 = 0; e2 < 2; ++e2) {
                float* dst = &part[(((w - 2) * MP) + mt * 4 + a) * 24 + vt * 8 + e2 * 4];
                float4 pv = *(const float4*)dst;
                pv.x += acc[a][e2 * 4];     pv.y += acc[a][e2 * 4 + 1];
                pv.z += acc[a][e2 * 4 + 2]; pv.w += acc[a][e2 * 4 + 3];
                *(float4*)dst = pv;
            }
        }
    }
    __syncthreads();

    for (int it = t; it < M3 * 6; it += 256) {
        int m = it / 6, vq = it % 6;
        float4 p0 = *(const float4*)&part[(m) * 24 + vq * 4];
        float4 p1 = *(const float4*)&part[(MP + m) * 24 + vq * 4];
        float bias = p_b[m];
        float4 s = make_float4(p0.x + p1.x + bias, p0.y + p1.y + bias,
                               p0.z + p1.z + bias, p0.w + p1.w + bias);
        *(float4*)&offset[((size_t)(b * M3 + m)) * SP + sp0 + vq * 4] = s;
    }
}

// ------------- Kernel B: sample + project, 4-lane-per-point gather ----------
// Phase 2: 4 lanes per sample point, each owning an 8-channel slice ->
// contiguous quarters of each 64B corner line (16 L1 lines/wave-load vs 64).
// Measured ~39us (r15). VGPR floor >=64 at (256,4) (r12: 48 VGPR = +50us).
__global__ __launch_bounds__(256, 4)
void sample_gemm_kernel(const unsigned short* __restrict__ x_t,
                        const float* __restrict__ offset,
                        const unsigned short* __restrict__ conv_wbf,
                        float* __restrict__ out,     // [2, 64, SP]
                        float* __restrict__ p_out) { // [2, SP, 81]
    // region: col[12][896] bf16 (21504 B) then s_corner[8][324] u32 (10368 B)
    __shared__ __align__(16) unsigned char region[VBB * CPAD * 2 + 8 * NV * 4];
    unsigned short* col = (unsigned short*)region;
    unsigned* s_corner = (unsigned*)(region + VBB * CPAD * 2);

    int bid = blockIdx.x;                    // 2304 = 2*24*24*2
    int r = bid & 1;
    int j = (bid >> 1) % 24;
    int i = ((bid >> 1) / 24) % 24;
    int b = bid / 1152;
    int k0 = r * VBB;
    int sp0 = i * 576 + j * 24 + k0;
    int t = threadIdx.x;

    const unsigned short* xtb = x_t + (size_t)b * SP * CC;

    // --- phase 1: corners + p_out ---
    for (int it = t; it < NV; it += 256) {
        int v = it % VBB, n = it / VBB;
        int sp = sp0 + v;
        int k = k0 + v;

        int pnx = n / 9 - 1, pny = (n / 3) % 3 - 1, pnz = n % 3 - 1;
        float p0a[3] = { (float)(i + 1 + pnx),
                         (float)(j + 1 + pny),
                         (float)(k + 1 + pnz) };
        int ql[3], qh[3];
        float wl[3], wh[3];
        #pragma unroll
        for (int ax = 0; ax < 3; ++ax) {
            int m = ax * NPTS + n;
            float p = p0a[ax] + offset[((size_t)(b * M3 + m)) * SP + sp];
            float f = floorf(p);
            int qlo = (int)fminf(fmaxf(f,       0.f), 25.f);
            int qhi = (int)fminf(fmaxf(f + 1.f, 0.f), 25.f);
            bool oob = (p < 1.f) || (p > 24.f);
            float pa = oob ? f : p;
            float pm = fminf(fmaxf(pa, 0.f), 25.f);
            ql[ax] = qlo; qh[ax] = qhi;
            wl[ax] = 1.f + ((float)qlo - pm);
            wh[ax] = 1.f - ((float)qhi - pm);
            p_out[((size_t)(b * SP + sp)) * M3 + m] = pm;
        }

        #pragma unroll
        for (int cr = 0; cr < 8; ++cr) {
            int ii = ((cr & 4) ? qh[0] : ql[0]) - 1;
            int jj = ((cr & 2) ? qh[1] : ql[1]) - 1;
            int kk = ((cr & 1) ? qh[2] : ql[2]) - 1;
            bool valid = ((unsigned)ii < (unsigned)DIM) &&
                         ((unsigned)jj < (unsigned)DIM) &&
                         ((unsigned)kk < (unsigned)DIM);
            float cw = ((cr & 4) ? wh[0] : wl[0]) *
                       ((cr & 2) ? wh[1] : wl[1]) *
                       ((cr & 1) ? wh[2] : wl[2]);
            unsigned idx = (unsigned)(ii * 576 + jj * 24 + kk);
            s_corner[cr * NV + it] =
                valid ? ((idx << 16) | (unsigned)f2bf(cw)) : 0u;
        }
    }
    __syncthreads();

    // --- phase 2: gather; 4 lanes per item, lane owns 8-channel slice q ---
    for (int task = t; task < NV * 4; task += 256) {
        int item = task >> 2, q = task & 3;
        int v = item % VBB, n = item / VBB;

        const unsigned short* xq = xtb + q * 8;
        float acc[8];
        #pragma unroll
        for (int e = 0; e < 8; ++e) acc[e] = 0.f;

        #pragma unroll
        for (int cr = 0; cr < 8; ++cr) {
            unsigned u = s_corner[cr * NV + item];
            float wc = __builtin_bit_cast(float, u << 16);
            const unsigned* s = (const unsigned*)(xq + (size_t)(u >> 16) * CC);
            #pragma unroll
            for (int q2 = 0; q2 < 4; ++q2) {
                unsigned uu = s[q2];
                acc[2 * q2]     += wc * __builtin_bit_cast(float, uu << 16);
                acc[2 * q2 + 1] += wc * __builtin_bit_cast(float, uu & 0xFFFF0000u);
            }
        }

        short8 pk;
        #pragma unroll
        for (int e = 0; e < 8; ++e)
            pk[e] = (short)f2bf(acc[e]);
        int sv = (v & 7) << 3;
        *(short8*)&col[v * CPAD + ((n * 32 + q * 8) ^ sv)] = pk;
    }
    __syncthreads();

    // --- phase 3: MFMA GEMM 64 x 864 @ 864 x 12 ---
    {
        int mt = t >> 6;                      // wave -> M tile (16 rows)
        int l = t & 63;
        int lr = l & 15;                      // A row / B col (voxel)
        int g = l >> 4;
        int sv = (lr & 7) << 3;

        const short8* ap =
            (const short8*)(conv_wbf + ((size_t)(mt * 16 + lr)) * CN + g * 8);
        const unsigned short* bp = col + lr * CPAD;

        f32x4 acc = {0.f, 0.f, 0.f, 0.f};
        #pragma unroll 3
        for (int kb = 0; kb < CN / 32; ++kb) {
            short8 a = ap[kb * 4];
            short8 bb = *(const short8*)&bp[(kb * 32 + g * 8) ^ sv];
            acc = __builtin_amdgcn_mfma_f32_16x16x32_bf16(a, bb, acc, 0, 0, 0);
        }
        if (lr < VBB) {
            float* op = out + ((size_t)(b * OUTC + mt * 16 + g * 4)) * SP + sp0 + lr;
            #pragma unroll
            for (int rr = 0; rr < 4; ++rr)
                op[(size_t)rr * SP] = acc[rr];
        }
    }
}

extern "C" void kernel_launch(void* const* d_in, const int* in_sizes, int n_in,
                              void* d_out, int out_size, void* d_ws, size_t ws_size,
                              hipStream_t stream) {
    const float* x      = (const float*)d_in[0];
    const float* p_w    = (const float*)d_in[1];
    const float* p_b    = (const float*)d_in[2];
    const float* conv_w = (const float*)d_in[3];

    float* out_all = (float*)d_out;
    float* out_main = out_all;                               // [2,64,13824]
    float* p_out    = out_all + (size_t)BATCH * OUTC * SP;   // [2,13824,81]

    float* offset          = (float*)d_ws;                   // [2,81,13824]
    float* p_wTP           = offset + (size_t)BATCH * M3 * SP;
    unsigned short* conv_wbf = (unsigned short*)(p_wTP + (size_t)CN * MP);
    unsigned short* x_t    = conv_wbf + (size_t)CN * OUTC;   // [2,13824,32] bf16

    {
        int total = CN * MP;                                 // 72576 covers both
        prep_w_kernel<<<(total + 255) / 256, 256, 0, stream>>>(p_w, conv_w,
                                                               p_wTP, conv_wbf);
    }
    {
        int blocks = BATCH * (SP / 64);                      // 432
        transpose_x_kernel<<<blocks, 256, 0, stream>>>(x, x_t);
    }
    {
        int blocks = BATCH * 24 * 24;                        // 1152
        offset_gemm_kernel<<<blocks, 256, 0, stream>>>(x, p_wTP, p_b, offset);
    }
    {
        int blocks = BATCH * 24 * 24 * 2;                    // 2304
        sample_gemm_kernel<<<blocks, 256, 0, stream>>>(x_t, offset, conv_wbf,
                                                       out_main, p_out);
    }
}